// Round 12
// baseline (662.271 us; speedup 1.0000x reference)
//
#include <hip/hip_runtime.h>
#include <hip/hip_bf16.h>

using f16x8 = __attribute__((ext_vector_type(8))) _Float16;
using f32x16 = __attribute__((ext_vector_type(16))) float;

union PackU { unsigned u; _Float16 h[2]; };

__device__ inline unsigned split_pack(float v) {
    _Float16 h0 = (_Float16)v;
    float r = (v - (float)h0) * 4096.0f;   // exact; scaled residual stays fp16-normal
    PackU p; p.h[0] = h0; p.h[1] = (_Float16)r;
    return p.u;
}

// async global->LDS, 16B per lane, dest = wave-uniform base + lane*16
__device__ __forceinline__ void gll16(const uint4* g, uint4* l) {
    __builtin_amdgcn_global_load_lds(
        (const __attribute__((address_space(1))) uint4*)g,
        (__attribute__((address_space(3))) uint4*)l, 16, 0, 0);
}

// fp32 -> packed {f16 hi, f16 lo*4096} pairs
__global__ __launch_bounds__(256) void split_kernel(const float* __restrict__ src,
                                                    unsigned* __restrict__ dst, int n4) {
    int g = blockIdx.x * 256 + threadIdx.x;
    if (g >= n4) return;
    float4 v = reinterpret_cast<const float4*>(src)[g];
    uint4 o;
    o.x = split_pack(v.x); o.y = split_pack(v.y);
    o.z = split_pack(v.z); o.w = split_pack(v.w);
    reinterpret_cast<uint4*>(dst)[g] = o;
}

// B preprocessing: fp32 [N][KK] row-major -> gll image (pre-swizzled LDS picture).
// Image: [npanel][kstep][1024 x uint4]; word w = r*8+c; c' = c ^ (r&7);
// plane p = c'>>2; kgroup = c'&3; uint4 = 8 u16 plane-p halves of k=kstep*32+kg*8..+7.
__global__ __launch_bounds__(256) void bsplit_gll(const float* __restrict__ src,
        uint4* __restrict__ dst, int KK, int nTilesK, int total) {
    int tid = blockIdx.x * 256 + threadIdx.x;
    if (tid >= total) return;
    int w = tid & 1023;
    int tile = tid >> 10;
    int kstep = tile % nTilesK;
    int npanel = tile / nTilesK;
    int r = w >> 3, c = w & 7;
    int cp = c ^ (r & 7);
    int p = cp >> 2, kg = cp & 3;
    int n = npanel * 128 + r;
    int k = kstep * 32 + kg * 8;
    const float* s = src + (size_t)n * KK + k;
    uint4 o;
    ushort* h = (ushort*)&o;
#pragma unroll
    for (int j = 0; j < 8; j++) {
        unsigned u = split_pack(s[j]);
        h[j] = p ? (ushort)(u >> 16) : (ushort)u;
    }
    dst[tid] = o;
}

#define BMt 128
#define BNt 128
#define BKt 32

// Split-fp16 MFMA gather-GEMM, 32x32x16 MFMA shape (r8-proven pipeline).
// A: reg-staged packed u32. B: async global_load_lds (pre-swizzled image), counted vmcnt.
// Fragment layout (32x32x16): lane holds row l&31, k=(l>>5)*8+j -> LDS chunk 2h+(l>>5).
// C/D (m74/m101 verified): col=lane&31, row=(reg&3)+8*(reg>>2)+4*(lane>>5).
// mode 0: OutP NCH packed = split(relu(acc+bias))        (conv1 -> hp)
// mode 1: OutF NCH fp32 (+bias) AND OutP[m][N] packed    (conv2 -> ze, zp)
// mode 2: fused argmin: atomicMin(mk[row], key(cn2[n]-2*acc, n))   (scores)
__global__ __launch_bounds__(256, 2) void mfma_gemm(
    const unsigned* __restrict__ Ap, const uint4* __restrict__ Bg,
    const float* __restrict__ bias,
    unsigned* __restrict__ OutP, float* __restrict__ OutF,
    const float* __restrict__ cn2v, unsigned long long* __restrict__ mk,
    int M, int N, int KK, int nTilesK, int Cc, int L, int Lout, int LoutSh,
    int gatherMode, int mode)
{
    __shared__ uint4 As4[2][BMt * 8];   // [buf][row*8+chunk], XOR-swizzled
    __shared__ uint4 Bs4[2][BNt * 8];

    const int tid = threadIdx.x;
    const int m0 = blockIdx.y * BMt;
    const int n0 = blockIdx.x * BNt;

    const int srow = tid >> 1;
    const int kh = tid & 1;
    const int sw_s = srow & 7;
    const int am = m0 + srow;
    const int ab = am >> LoutSh;
    const int at = am & (Lout - 1);
    const unsigned* aprow = Ap + (size_t)ab * Cc * L;
    const int ai0 = 2 * at - 1;
    const unsigned* adir = Ap + (size_t)am * KK;

    const int lane = tid & 63;
    const int wv = tid >> 6;
    const int wr = wv >> 1, wc = wv & 1;
    const int l31 = lane & 31, lh = lane >> 5;

    const uint4* bsrc = Bg + (size_t)blockIdx.x * nTilesK * 1024;

    f32x16 acc0[2][2] = {{{0.f}}};
    f32x16 acc1[2][2] = {{{0.f}}};

    uint4 pa[4];

    auto loadT = [&](int k0) {
        if (gatherMode) {
            int cbase = (k0 >> 2) + kh * 4;
#pragma unroll
            for (int cl = 0; cl < 4; cl++) {
                const unsigned* base = aprow + (size_t)(cbase + cl) * L;
                unsigned q0 = 0, q3 = 0;
                if (ai0 >= 0) q0 = base[ai0];           // only t==0 pads
                unsigned q1 = base[ai0 + 1];
                unsigned q2 = base[ai0 + 2];
                if (ai0 + 3 < L) q3 = base[ai0 + 3];    // only t==Lout-1 pads
                pa[cl].x = q0; pa[cl].y = q1; pa[cl].z = q2; pa[cl].w = q3;
            }
        } else {
            const uint4* s = reinterpret_cast<const uint4*>(adir + k0 + kh * 16);
#pragma unroll
            for (int q = 0; q < 4; q++) pa[q] = s[q];
        }
    };

    // A repack -> LDS (v_perm split, validated r4-r11)
    auto stage = [&](int buf) {
#pragma unroll
        for (int ch = 0; ch < 2; ch++) {
            uint4 w0, w1;
            unsigned* W0 = (unsigned*)&w0; unsigned* W1 = (unsigned*)&w1;
#pragma unroll
            for (int j = 0; j < 4; j++) {
                int e0 = ch * 8 + 2 * j, e1 = e0 + 1;
                unsigned lo = ((const unsigned*)&pa[e0 >> 2])[e0 & 3];
                unsigned hi = ((const unsigned*)&pa[e1 >> 2])[e1 & 3];
                W0[j] = __builtin_amdgcn_perm(hi, lo, 0x05040100u);
                W1[j] = __builtin_amdgcn_perm(hi, lo, 0x07060302u);
            }
            int kc = kh * 2 + ch;
            As4[buf][srow * 8 + ((kc) ^ sw_s)] = w0;
            As4[buf][srow * 8 + ((4 + kc) ^ sw_s)] = w1;
        }
    };

    // async B stage: 4 gll per wave
    auto gllB = [&](int buf, int kt2) {
        const uint4* ts = bsrc + (size_t)kt2 * 1024 + wv * 256 + lane;
#pragma unroll
        for (int i = 0; i < 4; i++)
            gll16(ts + i * 64, &Bs4[buf][wv * 256 + i * 64]);
    };

    const int NT = KK / BKt;

    loadT(0);          // A(0) vmem
    gllB(0, 0);        // B(0) gll
    stage(0);          // compiler waits A(0) only (gll newer, stays in flight)

    for (int kt = 0; kt < NT; kt++) {
        const int cur = kt & 1;
        if (kt + 1 < NT) loadT((kt + 1) * BKt);   // A(kt+1) issue

        // drain B(kt) only: A(kt+1) (16 or 4 newest) may stay outstanding.
        if (kt + 1 < NT) {
            if (gatherMode) asm volatile("s_waitcnt vmcnt(16)" ::: "memory");
            else            asm volatile("s_waitcnt vmcnt(4)" ::: "memory");
        } else {
            asm volatile("s_waitcnt vmcnt(0)" ::: "memory");
        }
        asm volatile("s_waitcnt lgkmcnt(0)\n\ts_barrier" ::: "memory");
        __builtin_amdgcn_sched_barrier(0);

        // WAR-safe here: all waves' reads of buf cur^1 drained at the barrier.
        if (kt + 1 < NT) gllB(cur ^ 1, kt + 1);

        // fragment reads: [mf][h] (h = k-half of the 32-k tile)
        f16x8 a0h[2][2], a1h[2][2];
#pragma unroll
        for (int mf = 0; mf < 2; mf++) {
            int arow = wr * 64 + mf * 32 + l31;
            int base = arow * 8, sw = arow & 7;
#pragma unroll
            for (int h = 0; h < 2; h++) {
                a0h[mf][h] = *reinterpret_cast<const f16x8*>(
                    &As4[cur][base + ((2 * h + lh) ^ sw)]);
                a1h[mf][h] = *reinterpret_cast<const f16x8*>(
                    &As4[cur][base + ((4 + 2 * h + lh) ^ sw)]);
            }
        }
        __builtin_amdgcn_s_setprio(1);
#pragma unroll
        for (int nf = 0; nf < 2; nf++) {
            int brow = wc * 64 + nf * 32 + l31;
            int base = brow * 8, sw = brow & 7;
            f16x8 b0h[2], b1h[2];
#pragma unroll
            for (int h = 0; h < 2; h++) {
                b0h[h] = *reinterpret_cast<const f16x8*>(
                    &Bs4[cur][base + ((2 * h + lh) ^ sw)]);
                b1h[h] = *reinterpret_cast<const f16x8*>(
                    &Bs4[cur][base + ((4 + 2 * h + lh) ^ sw)]);
            }
#pragma unroll
            for (int mf = 0; mf < 2; mf++) {
                acc0[mf][nf] = __builtin_amdgcn_mfma_f32_32x32x16_f16(
                    a0h[mf][0], b0h[0], acc0[mf][nf], 0, 0, 0);
                acc0[mf][nf] = __builtin_amdgcn_mfma_f32_32x32x16_f16(
                    a0h[mf][1], b0h[1], acc0[mf][nf], 0, 0, 0);
                acc1[mf][nf] = __builtin_amdgcn_mfma_f32_32x32x16_f16(
                    a0h[mf][0], b1h[0], acc1[mf][nf], 0, 0, 0);
                acc1[mf][nf] = __builtin_amdgcn_mfma_f32_32x32x16_f16(
                    a0h[mf][1], b1h[1], acc1[mf][nf], 0, 0, 0);
                acc1[mf][nf] = __builtin_amdgcn_mfma_f32_32x32x16_f16(
                    a1h[mf][0], b0h[0], acc1[mf][nf], 0, 0, 0);
                acc1[mf][nf] = __builtin_amdgcn_mfma_f32_32x32x16_f16(
                    a1h[mf][1], b0h[1], acc1[mf][nf], 0, 0, 0);
            }
        }
        __builtin_amdgcn_s_setprio(0);

        if (kt + 1 < NT) stage(cur ^ 1);   // compiler waits A(kt+1); gll(kt+1) stays out
    }

    const float s12 = 1.0f / 4096.0f;
    const int LoutM = Lout - 1;

    if (mode == 2) {
        // fused argmin over d2 = cn2[n] - 2*S; key = sortable(f32)<<32 | n
#pragma unroll
        for (int mf = 0; mf < 2; mf++) {
#pragma unroll
            for (int q = 0; q < 4; q++) {
#pragma unroll
                for (int j = 0; j < 4; j++) {
                    int row = m0 + wr * 64 + mf * 32 + q * 8 + 4 * lh + j;
                    unsigned long long best = ~0ull;
#pragma unroll
                    for (int nf = 0; nf < 2; nf++) {
                        int n = n0 + wc * 64 + nf * 32 + l31;
                        float s = acc0[mf][nf][q * 4 + j] + acc1[mf][nf][q * 4 + j] * s12;
                        float v = cn2v[n] - 2.f * s;
                        unsigned u = __float_as_uint(v);
                        unsigned sk = (u & 0x80000000u) ? ~u : (u | 0x80000000u);
                        unsigned long long key =
                            ((unsigned long long)sk << 32) | (unsigned)n;
                        if (key < best) best = key;
                    }
#pragma unroll
                    for (int msk = 1; msk < 32; msk <<= 1) {
                        unsigned long long o = __shfl_xor(best, msk);
                        if (o < best) best = o;
                    }
                    if (l31 == 0) atomicMin(&mk[row], best);
                }
            }
        }
    } else if (mode == 0) {
#pragma unroll
        for (int mf = 0; mf < 2; mf++) {
#pragma unroll
            for (int nf = 0; nf < 2; nf++) {
                int n = n0 + wc * 64 + nf * 32 + l31;
                float bv = bias[n];
#pragma unroll
                for (int q = 0; q < 4; q++) {
                    int mb = m0 + wr * 64 + mf * 32 + q * 8 + 4 * lh;
                    int b = mb >> LoutSh, t = mb & LoutM;
                    uint4 o;
                    unsigned* O = (unsigned*)&o;
#pragma unroll
                    for (int j = 0; j < 4; j++) {
                        float v = acc0[mf][nf][q * 4 + j]
                                + acc1[mf][nf][q * 4 + j] * s12 + bv;
                        v = fmaxf(v, 0.f);
                        O[j] = split_pack(v);
                    }
                    *reinterpret_cast<uint4*>(&OutP[((size_t)b * N + n) * Lout + t]) = o;
                }
            }
        }
    } else {  // mode 1
#pragma unroll
        for (int mf = 0; mf < 2; mf++) {
#pragma unroll
            for (int nf = 0; nf < 2; nf++) {
                int n = n0 + wc * 64 + nf * 32 + l31;
                float bv = bias[n];
#pragma unroll
                for (int q = 0; q < 4; q++) {
                    int mb = m0 + wr * 64 + mf * 32 + q * 8 + 4 * lh;
                    int b = mb >> LoutSh, t = mb & LoutM;
                    float4 f;
                    unsigned O[4];
#pragma unroll
                    for (int j = 0; j < 4; j++) {
                        float v = acc0[mf][nf][q * 4 + j]
                                + acc1[mf][nf][q * 4 + j] * s12 + bv;
                        ((float*)&f)[j] = v;
                        O[j] = split_pack(v);
                    }
                    *reinterpret_cast<float4*>(&OutF[((size_t)b * N + n) * Lout + t]) = f;
#pragma unroll
                    for (int j = 0; j < 4; j++)
                        OutP[(size_t)(mb + j) * N + n] = O[j];
                }
            }
        }
    }
}

// ||codebook_n||^2, one wave per row (fp32 exact)
__global__ __launch_bounds__(64) void cb_norm(const float* __restrict__ cb,
                                              float* __restrict__ cn2) {
    int n = blockIdx.x;
    int lane = threadIdx.x;
    float s = 0.f;
    for (int d = lane; d < 512; d += 64) {
        float v = cb[(size_t)n * 512 + d];
        s += v * v;
    }
#pragma unroll
    for (int off = 32; off; off >>= 1) s += __shfl_down(s, off);
    if (lane == 0) cn2[n] = s;
}

// minkeys -> idx (float) + z_q gather, one float4 per thread
__global__ __launch_bounds__(256) void finalize_k(
        const unsigned long long* __restrict__ mk, const float* __restrict__ cb,
        float* __restrict__ idxf, float* __restrict__ zq, int total4) {
    int g = blockIdx.x * 256 + threadIdx.x;
    if (g >= total4) return;
    int r = g >> 7;
    int d4 = g & 127;
    int id = (int)(unsigned)(mk[r] & 0xffffffffu);
    if (d4 == 0) idxf[r] = (float)id;
    *reinterpret_cast<float4*>(&zq[(size_t)r * 512 + (size_t)d4 * 4]) =
        *reinterpret_cast<const float4*>(&cb[(size_t)id * 512 + (size_t)d4 * 4]);
}

extern "C" void kernel_launch(void* const* d_in, const int* in_sizes, int n_in,
                              void* d_out, int out_size, void* d_ws, size_t ws_size,
                              hipStream_t stream) {
    const float* x  = (const float*)d_in[0];  // (32, 256, 2048)
    const float* w1 = (const float*)d_in[1];  // (1024, 256, 4) = [n][kk]
    const float* b1 = (const float*)d_in[2];
    const float* w2 = (const float*)d_in[3];  // (512, 1024, 4)
    const float* b2 = (const float*)d_in[4];
    const float* cb = (const float*)d_in[5];  // (1024, 512)
    float* out = (float*)d_out;

    const int B = 32, Cin = 256, T = 2048, H = 1024, D = 512, Kc = 1024;
    const int T1 = 1024, T2 = 512;

    float* zq_out  = out;                       // (B*T2, D)
    float* idx_out = out + (size_t)B * T2 * D;  // (B*T2,)
    float* ze_out  = idx_out + (size_t)B * T2;  // (B, D, T2)

    // ws layout (u32 units)
    unsigned* w1f = (unsigned*)d_ws;                       // H*Cin*4 u32 (image)
    unsigned* w2f = w1f + (size_t)H * Cin * 4;             // D*H*4 u32
    unsigned* cbf = w2f + (size_t)D * H * 4;               // Kc*D u32
    float* cn2    = (float*)(cbf + (size_t)Kc * D);        // Kc
    unsigned long long* mk = (unsigned long long*)(cn2 + Kc + 2);  // B*T2 u64
    unsigned* dyn = (unsigned*)(mk + (size_t)B * T2);

    size_t fixed_u32 = (size_t)H * Cin * 4 + (size_t)D * H * 4 + (size_t)Kc * D
                       + Kc + 2 * (size_t)B * T2 + 256;
    int NB = 32;
    while (NB > 1 &&
           (fixed_u32 + (size_t)NB * ((size_t)Cin * T + (size_t)H * T1 + (size_t)T2 * D))
               * 4 > ws_size)
        NB >>= 1;

    unsigned* xp = dyn;
    unsigned* hp = xp + (size_t)NB * Cin * T;
    unsigned* zp = hp + (size_t)NB * H * T1;

    bsplit_gll<<<(H * (Cin * 4) / 4 + 255) / 256, 256, 0, stream>>>(
        w1, (uint4*)w1f, Cin * 4, (Cin * 4) / 32, H * (Cin * 4) / 4);
    bsplit_gll<<<(D * (H * 4) / 4 + 255) / 256, 256, 0, stream>>>(
        w2, (uint4*)w2f, H * 4, (H * 4) / 32, D * (H * 4) / 4);
    bsplit_gll<<<(Kc * D / 4 + 255) / 256, 256, 0, stream>>>(
        cb, (uint4*)cbf, D, D / 32, Kc * D / 4);
    cb_norm<<<Kc, 64, 0, stream>>>(cb, cn2);
    hipMemsetAsync(mk, 0xFF, (size_t)B * T2 * 8, stream);   // keys = +inf

    for (int b0 = 0; b0 < B; b0 += NB) {
        int nb = (B - b0 < NB) ? (B - b0) : NB;

        split_kernel<<<(nb * Cin * T / 4 + 255) / 256, 256, 0, stream>>>(
            x + (size_t)b0 * Cin * T, xp, nb * Cin * T / 4);

        // conv1 + relu -> hp (packed NCH)
        mfma_gemm<<<dim3(H / BNt, nb * T1 / BMt), 256, 0, stream>>>(
            xp, (const uint4*)w1f, b1, hp, nullptr, nullptr, nullptr,
            nb * T1, H, Cin * 4, (Cin * 4) / 32, Cin, T, T1, 10, 1, 0);

        // conv2 -> ze (fp32 NCH) + zp (packed [m][D])
        mfma_gemm<<<dim3(D / BNt, nb * T2 / BMt), 256, 0, stream>>>(
            hp, (const uint4*)w2f, b2, zp, ze_out + (size_t)b0 * D * T2,
            nullptr, nullptr,
            nb * T2, D, H * 4, (H * 4) / 32, H, T1, T2, 9, 1, 1);

        // scores + fused argmin -> mk
        mfma_gemm<<<dim3(Kc / BNt, nb * T2 / BMt), 256, 0, stream>>>(
            zp, (const uint4*)cbf, nullptr, nullptr, nullptr,
            cn2, mk + (size_t)b0 * T2,
            nb * T2, Kc, D, D / 32, D, T2, T2, 9, 0, 2);

        // idx writeback + z_q gather
        finalize_k<<<(nb * T2 * D / 4 + 255) / 256, 256, 0, stream>>>(
            mk + (size_t)b0 * T2, cb, idx_out + (size_t)b0 * T2,
            zq_out + (size_t)b0 * T2 * D, nb * T2 * D / 4);
    }
}

// Round 13
// 565.601 us; speedup vs baseline: 1.1709x; 1.1709x over previous
//
#include <hip/hip_runtime.h>
#include <hip/hip_bf16.h>

using f16x8 = __attribute__((ext_vector_type(8))) _Float16;
using f32x4 = __attribute__((ext_vector_type(4))) float;

union PackU { unsigned u; _Float16 h[2]; };

__device__ inline unsigned split_pack(float v) {
    _Float16 h0 = (_Float16)v;
    float r = (v - (float)h0) * 4096.0f;   // exact; scaled residual stays fp16-normal
    PackU p; p.h[0] = h0; p.h[1] = (_Float16)r;
    return p.u;
}

// async global->LDS, 16B per lane, dest = wave-uniform base + lane*16
__device__ __forceinline__ void gll16(const uint4* g, uint4* l) {
    __builtin_amdgcn_global_load_lds(
        (const __attribute__((address_space(1))) uint4*)g,
        (__attribute__((address_space(3))) uint4*)l, 16, 0, 0);
}

// fp32 -> packed {f16 hi, f16 lo*4096} pairs
__global__ __launch_bounds__(256) void split_kernel(const float* __restrict__ src,
                                                    unsigned* __restrict__ dst, int n4) {
    int g = blockIdx.x * 256 + threadIdx.x;
    if (g >= n4) return;
    float4 v = reinterpret_cast<const float4*>(src)[g];
    uint4 o;
    o.x = split_pack(v.x); o.y = split_pack(v.y);
    o.z = split_pack(v.z); o.w = split_pack(v.w);
    reinterpret_cast<uint4*>(dst)[g] = o;
}

// B preprocessing: fp32 [N][KK] row-major -> gll image (pre-swizzled LDS picture).
// Image: [npanel][kstep][1024 x uint4]; word w = r*8+c; c' = c ^ (r&7);
// plane p = c'>>2; kgroup = c'&3; uint4 = 8 u16 plane-p halves of k=kstep*32+kg*8..+7.
__global__ __launch_bounds__(256) void bsplit_gll(const float* __restrict__ src,
        uint4* __restrict__ dst, int KK, int nTilesK, int total) {
    int tid = blockIdx.x * 256 + threadIdx.x;
    if (tid >= total) return;
    int w = tid & 1023;
    int tile = tid >> 10;
    int kstep = tile % nTilesK;
    int npanel = tile / nTilesK;
    int r = w >> 3, c = w & 7;
    int cp = c ^ (r & 7);
    int p = cp >> 2, kg = cp & 3;
    int n = npanel * 128 + r;
    int k = kstep * 32 + kg * 8;
    const float* s = src + (size_t)n * KK + k;
    uint4 o;
    ushort* h = (ushort*)&o;
#pragma unroll
    for (int j = 0; j < 8; j++) {
        unsigned u = split_pack(s[j]);
        h[j] = p ? (ushort)(u >> 16) : (ushort)u;
    }
    dst[tid] = o;
}

#define BMt 128
#define BNt 128
#define BKt 32

// Split-fp16 MFMA gather-GEMM (r8-proven loop) + XCD-chunked block swizzle.
// 1-D grid; orig = (h&7)*(nwg/8) + h/8 (bijective: nwg%8==0 guaranteed by host).
// bx = n-panel (2^gxShift panels), by = m-panel. Consecutive orig share by ->
// each XCD's contiguous chunk reuses A-panels in its own L2.
// A: reg-staged packed u32. B: async global_load_lds (pre-swizzled image),
// counted vmcnt (never drained mid-loop).
// mode 0: OutP NCH packed = split(relu(acc+bias))        (conv1 -> hp)
// mode 1: OutF NCH fp32 (+bias) AND OutP[m][N] packed    (conv2 -> ze, zp)
// mode 2: OutF[m][N] fp32                                 (scores)
__global__ __launch_bounds__(256, 2) void mfma_gemm(
    const unsigned* __restrict__ Ap, const uint4* __restrict__ Bg,
    const float* __restrict__ bias,
    unsigned* __restrict__ OutP, float* __restrict__ OutF,
    int M, int N, int KK, int nTilesK, int Cc, int L, int Lout, int LoutSh,
    int gatherMode, int mode, int gxShift)
{
    __shared__ uint4 As4[2][BMt * 8];   // [buf][row*8+chunk], XOR-swizzled
    __shared__ uint4 Bs4[2][BNt * 8];

    const int tid = threadIdx.x;
    const int nwg = gridDim.x;
    const int h = blockIdx.x;
    const int orig = (h & 7) * (nwg >> 3) + (h >> 3);   // XCD-chunked remap
    const int bx = orig & ((1 << gxShift) - 1);
    const int by = orig >> gxShift;
    const int m0 = by * BMt;
    const int n0 = bx * BNt;

    const int srow = tid >> 1;
    const int kh = tid & 1;
    const int sw_s = srow & 7;
    const int am = m0 + srow;
    const int ab = am >> LoutSh;
    const int at = am & (Lout - 1);
    const unsigned* aprow = Ap + (size_t)ab * Cc * L;
    const int ai0 = 2 * at - 1;
    const unsigned* adir = Ap + (size_t)am * KK;

    const int lane = tid & 63;
    const int wv = tid >> 6;
    const int wr = wv >> 1, wc = wv & 1;
    const int l15 = lane & 15, lq = lane >> 4;

    const uint4* bsrc = Bg + (size_t)bx * nTilesK * 1024;

    f32x4 acc0[4][4] = {{{0.f}}};
    f32x4 acc1[4][4] = {{{0.f}}};

    uint4 pa[4];

    auto loadT = [&](int k0) {
        if (gatherMode) {
            int cbase = (k0 >> 2) + kh * 4;
#pragma unroll
            for (int cl = 0; cl < 4; cl++) {
                const unsigned* base = aprow + (size_t)(cbase + cl) * L;
                unsigned q0 = 0, q3 = 0;
                if (ai0 >= 0) q0 = base[ai0];           // only t==0 pads
                unsigned q1 = base[ai0 + 1];
                unsigned q2 = base[ai0 + 2];
                if (ai0 + 3 < L) q3 = base[ai0 + 3];    // only t==Lout-1 pads
                pa[cl].x = q0; pa[cl].y = q1; pa[cl].z = q2; pa[cl].w = q3;
            }
        } else {
            const uint4* s = reinterpret_cast<const uint4*>(adir + k0 + kh * 16);
#pragma unroll
            for (int q = 0; q < 4; q++) pa[q] = s[q];
        }
    };

    // A repack -> LDS (v_perm split, validated r4-r12)
    auto stage = [&](int buf) {
#pragma unroll
        for (int ch = 0; ch < 2; ch++) {
            uint4 w0, w1;
            unsigned* W0 = (unsigned*)&w0; unsigned* W1 = (unsigned*)&w1;
#pragma unroll
            for (int j = 0; j < 4; j++) {
                int e0 = ch * 8 + 2 * j, e1 = e0 + 1;
                unsigned lo = ((const unsigned*)&pa[e0 >> 2])[e0 & 3];
                unsigned hi = ((const unsigned*)&pa[e1 >> 2])[e1 & 3];
                W0[j] = __builtin_amdgcn_perm(hi, lo, 0x05040100u);
                W1[j] = __builtin_amdgcn_perm(hi, lo, 0x07060302u);
            }
            int kc = kh * 2 + ch;
            As4[buf][srow * 8 + ((kc) ^ sw_s)] = w0;
            As4[buf][srow * 8 + ((4 + kc) ^ sw_s)] = w1;
        }
    };

    // async B stage: 4 gll per wave
    auto gllB = [&](int buf, int kt2) {
        const uint4* ts = bsrc + (size_t)kt2 * 1024 + wv * 256 + lane;
#pragma unroll
        for (int i = 0; i < 4; i++)
            gll16(ts + i * 64, &Bs4[buf][wv * 256 + i * 64]);
    };

    const int NT = KK / BKt;

    loadT(0);          // A(0) vmem
    gllB(0, 0);        // B(0) gll
    stage(0);          // compiler waits A(0) only (gll newer, stays in flight)

    for (int kt = 0; kt < NT; kt++) {
        const int cur = kt & 1;
        if (kt + 1 < NT) loadT((kt + 1) * BKt);   // A(kt+1) issue

        // drain B(kt) only: A(kt+1) (16 or 4 newest) may stay outstanding.
        if (kt + 1 < NT) {
            if (gatherMode) asm volatile("s_waitcnt vmcnt(16)" ::: "memory");
            else            asm volatile("s_waitcnt vmcnt(4)" ::: "memory");
        } else {
            asm volatile("s_waitcnt vmcnt(0)" ::: "memory");
        }
        asm volatile("s_waitcnt lgkmcnt(0)\n\ts_barrier" ::: "memory");
        __builtin_amdgcn_sched_barrier(0);

        // WAR-safe here: all waves' reads of buf cur^1 drained at the barrier.
        if (kt + 1 < NT) gllB(cur ^ 1, kt + 1);

        f16x8 a0f[4], a1f[4];
#pragma unroll
        for (int mf = 0; mf < 4; mf++) {
            int row = wr * 64 + mf * 16 + l15;
            int sw = row & 7;
            a0f[mf] = *reinterpret_cast<const f16x8*>(&As4[cur][row * 8 + (lq ^ sw)]);
            a1f[mf] = *reinterpret_cast<const f16x8*>(&As4[cur][row * 8 + ((4 + lq) ^ sw)]);
        }
        __builtin_amdgcn_s_setprio(1);
#pragma unroll
        for (int nf = 0; nf < 4; nf++) {
            int row = wc * 64 + nf * 16 + l15;
            int sw = row & 7;
            f16x8 b0f = *reinterpret_cast<const f16x8*>(&Bs4[cur][row * 8 + (lq ^ sw)]);
            f16x8 b1f = *reinterpret_cast<const f16x8*>(&Bs4[cur][row * 8 + ((4 + lq) ^ sw)]);
#pragma unroll
            for (int mf = 0; mf < 4; mf++) {
                acc0[mf][nf] = __builtin_amdgcn_mfma_f32_16x16x32_f16(
                    a0f[mf], b0f, acc0[mf][nf], 0, 0, 0);
                acc1[mf][nf] = __builtin_amdgcn_mfma_f32_16x16x32_f16(
                    a0f[mf], b1f, acc1[mf][nf], 0, 0, 0);
                acc1[mf][nf] = __builtin_amdgcn_mfma_f32_16x16x32_f16(
                    a1f[mf], b0f, acc1[mf][nf], 0, 0, 0);
            }
        }
        __builtin_amdgcn_s_setprio(0);

        if (kt + 1 < NT) stage(cur ^ 1);   // compiler waits A(kt+1); gll(kt+1) stays out
    }

    const float s12 = 1.0f / 4096.0f;
    const int LoutM = Lout - 1;

    if (mode == 2) {
#pragma unroll
        for (int mf = 0; mf < 4; mf++) {
            int mb = m0 + wr * 64 + mf * 16 + lq * 4;
#pragma unroll
            for (int nf = 0; nf < 4; nf++) {
                int n = n0 + wc * 64 + nf * 16 + l15;
#pragma unroll
                for (int r = 0; r < 4; r++) {
                    float v = acc0[mf][nf][r] + acc1[mf][nf][r] * s12;
                    OutF[(size_t)(mb + r) * N + n] = v;
                }
            }
        }
    } else if (mode == 0) {
#pragma unroll
        for (int mf = 0; mf < 4; mf++) {
            int mb = m0 + wr * 64 + mf * 16 + lq * 4;
            int b = mb >> LoutSh, t = mb & LoutM;
#pragma unroll
            for (int nf = 0; nf < 4; nf++) {
                int n = n0 + wc * 64 + nf * 16 + l15;
                float bv = bias[n];
                uint4 o;
                unsigned* O = (unsigned*)&o;
#pragma unroll
                for (int r = 0; r < 4; r++) {
                    float v = acc0[mf][nf][r] + acc1[mf][nf][r] * s12 + bv;
                    v = fmaxf(v, 0.f);
                    O[r] = split_pack(v);
                }
                *reinterpret_cast<uint4*>(&OutP[((size_t)b * N + n) * Lout + t]) = o;
            }
        }
    } else {  // mode 1
#pragma unroll
        for (int mf = 0; mf < 4; mf++) {
            int mb = m0 + wr * 64 + mf * 16 + lq * 4;
            int b = mb >> LoutSh, t = mb & LoutM;
#pragma unroll
            for (int nf = 0; nf < 4; nf++) {
                int n = n0 + wc * 64 + nf * 16 + l15;
                float bv = bias[n];
                float4 f;
                unsigned O[4];
#pragma unroll
                for (int r = 0; r < 4; r++) {
                    float v = acc0[mf][nf][r] + acc1[mf][nf][r] * s12 + bv;
                    ((float*)&f)[r] = v;
                    O[r] = split_pack(v);
                }
                *reinterpret_cast<float4*>(&OutF[((size_t)b * N + n) * Lout + t]) = f;
#pragma unroll
                for (int r = 0; r < 4; r++)
                    OutP[(size_t)(mb + r) * N + n] = O[r];
            }
        }
    }
}

// ||codebook_n||^2, one wave per row (fp32 exact)
__global__ __launch_bounds__(64) void cb_norm(const float* __restrict__ cb,
                                              float* __restrict__ cn2) {
    int n = blockIdx.x;
    int lane = threadIdx.x;
    float s = 0.f;
    for (int d = lane; d < 512; d += 64) {
        float v = cb[(size_t)n * 512 + d];
        s += v * v;
    }
#pragma unroll
    for (int off = 32; off; off >>= 1) s += __shfl_down(s, off);
    if (lane == 0) cn2[n] = s;
}

// argmin over (cn2[n] - 2*S[r][n]); one wave per row, first-occurrence ties
__global__ __launch_bounds__(256) void argmin_k(const float* __restrict__ S,
                                                const float* __restrict__ cn2,
                                                float* __restrict__ idxf,
                                                int* __restrict__ idxi, int rows) {
    int wid = threadIdx.x >> 6;
    int lane = threadIdx.x & 63;
    int r = blockIdx.x * 4 + wid;
    if (r >= rows) return;
    const float* srow = S + (size_t)r * 1024;
    float best = INFINITY;
    int bi = 0;
#pragma unroll
    for (int it = 0; it < 4; it++) {
        int nb = it * 256 + lane * 4;
        float4 s4 = *reinterpret_cast<const float4*>(&srow[nb]);
        float4 c4 = *reinterpret_cast<const float4*>(&cn2[nb]);
        float v;
        v = c4.x - 2.f * s4.x; if (v < best) { best = v; bi = nb + 0; }
        v = c4.y - 2.f * s4.y; if (v < best) { best = v; bi = nb + 1; }
        v = c4.z - 2.f * s4.z; if (v < best) { best = v; bi = nb + 2; }
        v = c4.w - 2.f * s4.w; if (v < best) { best = v; bi = nb + 3; }
    }
#pragma unroll
    for (int off = 32; off; off >>= 1) {
        float ov = __shfl_down(best, off);
        int oi = __shfl_down(bi, off);
        if (ov < best || (ov == best && oi < bi)) { best = ov; bi = oi; }
    }
    if (lane == 0) {
        idxf[r] = (float)bi;
        idxi[r] = bi;
    }
}

// z_q[r][:] = codebook[idx[r]][:]
__global__ __launch_bounds__(256) void gather_k(const int* __restrict__ idx,
                                                const float* __restrict__ cb,
                                                float* __restrict__ zq, int total4) {
    int g = blockIdx.x * 256 + threadIdx.x;
    if (g >= total4) return;
    int r = g >> 7;
    int d4 = g & 127;
    int id = idx[r];
    *reinterpret_cast<float4*>(&zq[(size_t)r * 512 + (size_t)d4 * 4]) =
        *reinterpret_cast<const float4*>(&cb[(size_t)id * 512 + (size_t)d4 * 4]);
}

extern "C" void kernel_launch(void* const* d_in, const int* in_sizes, int n_in,
                              void* d_out, int out_size, void* d_ws, size_t ws_size,
                              hipStream_t stream) {
    const float* x  = (const float*)d_in[0];  // (32, 256, 2048)
    const float* w1 = (const float*)d_in[1];  // (1024, 256, 4) = [n][kk]
    const float* b1 = (const float*)d_in[2];
    const float* w2 = (const float*)d_in[3];  // (512, 1024, 4)
    const float* b2 = (const float*)d_in[4];
    const float* cb = (const float*)d_in[5];  // (1024, 512)
    float* out = (float*)d_out;

    const int B = 32, Cin = 256, T = 2048, H = 1024, D = 512, Kc = 1024;
    const int T1 = 1024, T2 = 512;

    float* zq_out  = out;                       // (B*T2, D)
    float* idx_out = out + (size_t)B * T2 * D;  // (B*T2,)
    float* ze_out  = idx_out + (size_t)B * T2;  // (B, D, T2)

    // ws layout (u32 units); B images same byte size as old packed arrays
    unsigned* w1f = (unsigned*)d_ws;                       // H*Cin*4 u32 (image)
    unsigned* w2f = w1f + (size_t)H * Cin * 4;             // D*H*4 u32
    unsigned* cbf = w2f + (size_t)D * H * 4;               // Kc*D u32
    float* cn2    = (float*)(cbf + (size_t)Kc * D);        // Kc
    int* idx_ws   = (int*)(cn2 + Kc);                      // B*T2
    unsigned* dyn = (unsigned*)(idx_ws + B * T2);

    size_t fixed_u32 = (size_t)H * Cin * 4 + (size_t)D * H * 4 + (size_t)Kc * D
                       + Kc + (size_t)B * T2 + 256;
    int NB = 32;
    while (NB > 1 &&
           (fixed_u32 + (size_t)NB * ((size_t)Cin * T + (size_t)H * T1 + (size_t)T2 * D))
               * 4 > ws_size)
        NB >>= 1;

    unsigned* xp = dyn;
    unsigned* hp = xp + (size_t)NB * Cin * T;
    unsigned* zp = hp + (size_t)NB * H * T1;
    float* S = (float*)hp;   // overlays hp (dead when scores run)

    bsplit_gll<<<(H * (Cin * 4) / 4 + 255) / 256, 256, 0, stream>>>(
        w1, (uint4*)w1f, Cin * 4, (Cin * 4) / 32, H * (Cin * 4) / 4);
    bsplit_gll<<<(D * (H * 4) / 4 + 255) / 256, 256, 0, stream>>>(
        w2, (uint4*)w2f, H * 4, (H * 4) / 32, D * (H * 4) / 4);
    bsplit_gll<<<(Kc * D / 4 + 255) / 256, 256, 0, stream>>>(
        cb, (uint4*)cbf, D, D / 32, Kc * D / 4);
    cb_norm<<<Kc, 64, 0, stream>>>(cb, cn2);

    for (int b0 = 0; b0 < B; b0 += NB) {
        int nb = (B - b0 < NB) ? (B - b0) : NB;

        split_kernel<<<(nb * Cin * T / 4 + 255) / 256, 256, 0, stream>>>(
            x + (size_t)b0 * Cin * T, xp, nb * Cin * T / 4);

        // conv1 + relu -> hp (packed NCH); grid = 8 n-panels x (nb*8) m-panels
        mfma_gemm<<<(H / BNt) * (nb * T1 / BMt), 256, 0, stream>>>(
            xp, (const uint4*)w1f, b1, hp, nullptr,
            nb * T1, H, Cin * 4, (Cin * 4) / 32, Cin, T, T1, 10, 1, 0, /*gxShift*/3);

        // conv2 -> ze (fp32 NCH) + zp (packed [m][D]); 4 n-panels
        mfma_gemm<<<(D / BNt) * (nb * T2 / BMt), 256, 0, stream>>>(
            hp, (const uint4*)w2f, b2, zp, ze_out + (size_t)b0 * D * T2,
            nb * T2, D, H * 4, (H * 4) / 32, H, T1, T2, 9, 1, 1, /*gxShift*/2);

        // scores S[m][n] = z . cb; 8 n-panels
        mfma_gemm<<<(Kc / BNt) * (nb * T2 / BMt), 256, 0, stream>>>(
            zp, (const uint4*)cbf, nullptr, nullptr, S,
            nb * T2, Kc, D, D / 32, D, T2, T2, 9, 0, 2, /*gxShift*/3);

        argmin_k<<<(nb * T2 + 3) / 4, 256, 0, stream>>>(
            S, cn2, idx_out + (size_t)b0 * T2, idx_ws, nb * T2);

        gather_k<<<(nb * T2 * D / 4 + 255) / 256, 256, 0, stream>>>(
            idx_ws, cb, zq_out + (size_t)b0 * T2 * D, nb * T2 * D / 4);
    }
}